// Round 1
// baseline (1103.636 us; speedup 1.0000x reference)
//
#include <hip/hip_runtime.h>
#include <hip/hip_bf16.h>

// Row-gather: out[token, 0:ple_dim] = table[ids[token], start : start+ple_dim]
// where start = layer_idx * ple_dim, table row stride = HIDDEN floats.
//
// Layout: vec_per_token = ple_dim/4 float4's per token. Each thread handles
// one float4: lane-within-group = column, group = token. With ple_dim=256,
// vec_per_token=64 (= one wave per token), 256-thread blocks = 4 tokens/block.

__global__ __launch_bounds__(256) void ple_gather_kernel(
    const int* __restrict__ ids,          // [n_tokens]
    const float* __restrict__ table,      // [VOCAB, hidden]
    const int* __restrict__ layer_idx_p,  // device scalar
    float* __restrict__ out,              // [n_tokens, ple_dim]
    int n_tokens,
    int hidden,
    int ple_dim,
    int vec_per_token,     // ple_dim / 4
    int tokens_per_block)  // blockDim.x / vec_per_token
{
    const int local_tok = threadIdx.x / vec_per_token;
    const int col4      = threadIdx.x % vec_per_token;
    const int token     = blockIdx.x * tokens_per_block + local_tok;
    if (token >= n_tokens) return;

    const int start = layer_idx_p[0] * ple_dim;  // uniform broadcast load

    const int id = ids[token];
    const float4* src = (const float4*)(table + (size_t)id * (size_t)hidden + start) + col4;
    float4* dst = (float4*)(out + (size_t)token * (size_t)ple_dim) + col4;
    *dst = *src;
}

extern "C" void kernel_launch(void* const* d_in, const int* in_sizes, int n_in,
                              void* d_out, int out_size, void* d_ws, size_t ws_size,
                              hipStream_t stream) {
    const int*   ids       = (const int*)d_in[0];
    const float* table     = (const float*)d_in[1];
    const int*   layer_idx = (const int*)d_in[2];
    // d_in[3] is ple_dim as a device scalar; we derive it host-side instead:
    const int n_tokens = in_sizes[0];                 // B*S = 16384
    const int ple_dim  = out_size / n_tokens;         // 256
    const int hidden   = 2048;                        // reference HIDDEN (row stride)

    const int vec_per_token    = ple_dim / 4;         // 64
    const int block            = 256;
    const int tokens_per_block = block / vec_per_token;  // 4
    const int grid = (n_tokens + tokens_per_block - 1) / tokens_per_block;  // 4096

    ple_gather_kernel<<<grid, block, 0, stream>>>(
        ids, table, layer_idx, (float*)d_out,
        n_tokens, hidden, ple_dim, vec_per_token, tokens_per_block);
}